// Round 21
// baseline (136.401 us; speedup 1.0000x reference)
//
#include <hip/hip_runtime.h>
#include <math.h>

#define N_NODES 10000
#define N_EDGES 160000
#define NEL 10
#define C 64
#define NB 8
#define SHD 9
#define MLPH 16
#define CSH 576
#define R_MAX 5.0f
#define INV_AVG 0.03125f
#define SCAN_CH2 10    // 1024*10 = 10240 >= N_NODES
#define ROWP  584      // f16 row pitch of LDS agg tile (bank-safe)

typedef _Float16 f16x2 __attribute__((ext_vector_type(2)));
typedef _Float16 f16x8 __attribute__((ext_vector_type(8)));
typedef float    f32x4 __attribute__((ext_vector_type(4)));
typedef _Float16 half_t;

__device__ __forceinline__ float silu_f(float v) {
    return v / (1.0f + __expf(-v));
}

__device__ __forceinline__ float dot2f(f16x2 a, f16x2 b, float c) {
#if __has_builtin(__builtin_amdgcn_fdot2)
    return __builtin_amdgcn_fdot2(a, b, c, false);
#else
    return c + (float)a.x * (float)b.x + (float)a.y * (float)b.y;
#endif
}

// ---------------------------------------------------------------------------
// K0: zero cnt + deg
// ---------------------------------------------------------------------------
__global__ __launch_bounds__(256) void k_zero(
    int* __restrict__ cnt, int* __restrict__ deg)
{
    int i = blockIdx.x * 256 + threadIdx.x;
    if (i == 0) *cnt = 0;
    if (i < N_NODES) deg[i] = 0;
}

// ---------------------------------------------------------------------------
// K1: per-edge geometry + radial basis + compaction + degree histogram +
// fused embed (hh = f16 h) + ALL weight packing on idle blocks (>= 625).
// ---------------------------------------------------------------------------
__global__ __launch_bounds__(256) void k_edge(
    const float* __restrict__ pos, const float* __restrict__ shifts,
    const int* __restrict__ ei,
    const float* __restrict__ na, const float* __restrict__ We,
    const float* __restrict__ ae,
    const float* __restrict__ Wr2, const float* __restrict__ Wmix,
    const float* __restrict__ Wself, const float* __restrict__ Wup,
    int* __restrict__ cnt, int* __restrict__ deg,
    int* __restrict__ act_snd, int* __restrict__ act_rcv,
    float* __restrict__ act_u, float* __restrict__ act_ef,
    f16x2* __restrict__ wlth, f16x8* __restrict__ wmixf, f16x8* __restrict__ wupf,
    half_t* __restrict__ hh, float* __restrict__ out)
{
    int i = blockIdx.x * 256 + threadIdx.x;
    int lane = threadIdx.x & 63;

    // ---- embed: h = na @ We ; out = na @ ae ----
    {
        int n = i >> 6;
        float acc = 0.0f, e0 = 0.0f;
        #pragma unroll
        for (int k = 0; k < NEL; k++) {
            float a = na[n * NEL + k];
            acc += a * We[k * C + lane];
            e0 += a * ae[k];
        }
        hh[i] = (half_t)acc;
        if (lane == 0) out[n] = e0;
    }

    if (blockIdx.x >= N_EDGES / 256) {
        // ---- weight packing on idle blocks ----
        int idx = i - N_EDGES;
        if (idx < 2 * 8 * CSH) {               // wlth: 9216
            int t = idx / (8 * CSH);
            int r = idx - t * (8 * CSH);
            int mq = r / CSH, j = r - mq * CSH;
            int c = j & 63, s = j >> 6;
            float lo = Wr2[t * MLPH * CSH + (2 * mq + 0) * CSH + c * SHD + s];
            float hi = Wr2[t * MLPH * CSH + (2 * mq + 1) * CSH + c * SHD + s];
            f16x2 v; v.x = (_Float16)lo; v.y = (_Float16)hi;
            wlth[idx] = v;
        } else if (idx < 2 * 8 * CSH + 10240) { // wmixf
            int k2 = idx - 2 * 8 * CSH;
            int t = k2 / 5120;
            int r = k2 - t * 5120;
            int ks = r >> 8;
            int rr = r & 255;
            int nt = rr >> 6;
            int ln = rr & 63;
            f16x8 v;
            #pragma unroll
            for (int e = 0; e < 8; e++) {
                int k = ks * 32 + ((ln >> 4) << 3) + e;
                int col = nt * 16 + (ln & 15);
                float x;
                if (k < CSH)
                    x = Wmix[(size_t)t * CSH * C + ((k & 63) * SHD + (k >> 6)) * C + col] * INV_AVG;
                else
                    x = Wself[(size_t)t * C * C + (k - CSH) * C + col];
                v[e] = (_Float16)x;
            }
            wmixf[(size_t)((t * 20 + ks) * 4 + nt) * 64 + ln] = v;
        } else if (idx < 2 * 8 * CSH + 10240 + 1024) {  // wupf
            int k2 = idx - (2 * 8 * CSH + 10240);
            int t = k2 >> 9;
            int r = k2 & 511;
            int ks = r >> 8;
            int rr = r & 255;
            int nt = rr >> 6;
            int ln = rr & 63;
            f16x8 v;
            #pragma unroll
            for (int e = 0; e < 8; e++) {
                int k = ks * 32 + ((ln >> 4) << 3) + e;
                int col = nt * 16 + (ln & 15);
                v[e] = (_Float16)Wup[(size_t)t * C * C + k * C + col];
            }
            wupf[(size_t)((t * 2 + ks) * 4 + nt) * 64 + ln] = v;
        }
        return;
    }

    int e = i;
    int snd = ei[e];
    int rcv = ei[N_EDGES + e];
    float vx = pos[rcv * 3 + 0] - pos[snd * 3 + 0] + shifts[e * 3 + 0];
    float vy = pos[rcv * 3 + 1] - pos[snd * 3 + 1] + shifts[e * 3 + 1];
    float vz = pos[rcv * 3 + 2] - pos[snd * 3 + 2] + shifts[e * 3 + 2];
    float r = sqrtf(vx * vx + vy * vy + vz * vz) + 1e-9f;
    float x = r / R_MAX;
    bool active = x < 1.0f;

    unsigned long long m = __ballot(active);
    int base = 0;
    if (m) {
        int leader = __ffsll((unsigned long long)m) - 1;
        if (lane == leader) base = atomicAdd(cnt, __popcll(m));
        base = __shfl(base, leader);
    }
    if (!active) return;

    int p = base + __popcll(m & ((1ull << lane) - 1ull));
    act_snd[p] = snd;
    act_rcv[p] = rcv;
    atomicAdd(&deg[rcv], 1);

    float inv_r = 1.0f / r;
    *(float4*)&act_u[p * 4] = make_float4(vx * inv_r, vy * inv_r, vz * inv_r, r);

    float x6 = x * x * x; x6 = x6 * x6;
    float x7 = x6 * x;
    float x8 = x7 * x;
    float fc = 1.0f - 28.0f * x6 + 48.0f * x7 - 21.0f * x8;
    float theta = 3.14159265358979323846f * r / R_MAX;
    float s1 = sinf(theta), c1 = cosf(theta);
    float sn = s1, cn = c1;
    float scale = 0.6324555320336759f * inv_r * fc;   // sqrt(2/R_MAX)/r*fc
    float ef[NB];
    ef[0] = scale * sn;
    #pragma unroll
    for (int n = 1; n < NB; n++) {
        float sn1 = sn * c1 + cn * s1;
        float cn1 = cn * c1 - sn * s1;
        sn = sn1; cn = cn1;
        ef[n] = scale * sn;
    }
    *(float4*)&act_ef[p * 8 + 0] = make_float4(ef[0], ef[1], ef[2], ef[3]);
    *(float4*)&act_ef[p * 8 + 4] = make_float4(ef[4], ef[5], ef[6], ef[7]);
}

// ---------------------------------------------------------------------------
// K1b (merged scan + upm): block 0 = exclusive scan of deg -> rowptr+cursor
// (1024 threads). Blocks 1..40: wave W computes hup MFMA tile.
// ---------------------------------------------------------------------------
__global__ __launch_bounds__(1024) void k_scan_up(
    const int* __restrict__ deg, int* __restrict__ rowptr, int* __restrict__ cursor,
    const half_t* __restrict__ hh, const f16x8* __restrict__ wupf,
    float* __restrict__ hup)
{
    int tid = threadIdx.x;

    if (blockIdx.x != 0) {
        int F = (blockIdx.x - 1) * 16 + (tid >> 6);
        if (F >= N_NODES / 16) return;
        int lane = tid & 63;
        int base = F * 16;
        int rowA = base + (lane & 15);
        int kg = (lane >> 4) << 3;

        f32x4 u0 = {0.f,0.f,0.f,0.f}, u1 = {0.f,0.f,0.f,0.f};
        f32x4 u2 = {0.f,0.f,0.f,0.f}, u3 = {0.f,0.f,0.f,0.f};
        const half_t* hrow = hh + (size_t)rowA * C + kg;
        #pragma unroll
        for (int ks = 0; ks < 2; ks++) {
            f16x8 a = *(const f16x8*)(hrow + ks * 32);
            const f16x8* bp = wupf + (size_t)(ks * 4) * 64 + lane;
            u0 = __builtin_amdgcn_mfma_f32_16x16x32_f16(a, bp[0],   u0, 0, 0, 0);
            u1 = __builtin_amdgcn_mfma_f32_16x16x32_f16(a, bp[64],  u1, 0, 0, 0);
            u2 = __builtin_amdgcn_mfma_f32_16x16x32_f16(a, bp[128], u2, 0, 0, 0);
            u3 = __builtin_amdgcn_mfma_f32_16x16x32_f16(a, bp[192], u3, 0, 0, 0);
        }
        int colb = lane & 15;
        int rowb = base + ((lane >> 4) << 2);
        #pragma unroll
        for (int r = 0; r < 4; r++) {
            float* hp = hup + (size_t)(rowb + r) * C + colb;
            hp[0]  = u0[r];
            hp[16] = u1[r];
            hp[32] = u2[r];
            hp[48] = u3[r];
        }
        return;
    }

    __shared__ int dl[N_NODES];   // 40000 B
    __shared__ int part[1024];    // 4096 B
    for (int i = tid; i < N_NODES; i += 1024) dl[i] = deg[i];
    __syncthreads();

    int base = tid * SCAN_CH2;
    int s = 0;
    #pragma unroll
    for (int i = 0; i < SCAN_CH2; i++) {
        int idx = base + i;
        if (idx < N_NODES) s += dl[idx];
    }
    part[tid] = s;
    __syncthreads();
    for (int off = 1; off < 1024; off <<= 1) {
        int v = (tid >= off) ? part[tid - off] : 0;
        __syncthreads();
        part[tid] += v;
        __syncthreads();
    }
    int run = part[tid] - s;
    #pragma unroll
    for (int i = 0; i < SCAN_CH2; i++) {
        int idx = base + i;
        if (idx < N_NODES) {
            int v = dl[idx];
            dl[idx] = run;
            run += v;
        }
    }
    __syncthreads();
    for (int i = tid; i < N_NODES; i += 1024) {
        int r = dl[i];
        rowptr[i] = r;
        cursor[i] = r;
    }
    if (tid == 1023) rowptr[N_NODES] = part[1023];
}

// ---------------------------------------------------------------------------
// K1c (merged rank+permute): scatter payloads into CSR order directly.
// ---------------------------------------------------------------------------
__global__ __launch_bounds__(256) void k_scatter(
    const int* __restrict__ cnt, const int* __restrict__ act_snd,
    const int* __restrict__ act_rcv, const float* __restrict__ act_u,
    const float* __restrict__ act_ef, const float* __restrict__ Wr1,
    int* __restrict__ cursor,
    int* __restrict__ csnd, int* __restrict__ crcv, float* __restrict__ csh,
    f16x2* __restrict__ chidh0, f16x2* __restrict__ chidh1)
{
    int i = blockIdx.x * 256 + threadIdx.x;
    if (i >= *cnt) return;
    int rcv = act_rcv[i];
    int p = atomicAdd(&cursor[rcv], 1);

    csnd[p] = act_snd[i];
    crcv[p] = rcv;

    float4 u4 = *(const float4*)&act_u[i * 4];
    float ux = u4.x, uy = u4.y, uz = u4.z;
    const float s3 = 1.7320508075688772f;
    const float s5 = 2.23606797749979f;
    const float s15 = 3.872983346207417f;
    *(float4*)&csh[p * 16 + 0] = make_float4(1.0f, s3 * ux, s3 * uy, s3 * uz);
    *(float4*)&csh[p * 16 + 4] = make_float4(s15 * ux * uy, s15 * uy * uz,
                                             0.5f * s5 * (3.0f * uz * uz - 1.0f),
                                             s15 * ux * uz);
    csh[p * 16 + 8] = 0.5f * s15 * (ux * ux - uy * uy);

    float4 e0 = *(const float4*)&act_ef[i * 8 + 0];
    float4 e1 = *(const float4*)&act_ef[i * 8 + 4];
    float ef[NB] = {e0.x, e0.y, e0.z, e0.w, e1.x, e1.y, e1.z, e1.w};

    #pragma unroll
    for (int t = 0; t < 2; t++) {
        f16x2* dst = (t == 0) ? chidh0 : chidh1;
        const float* W = Wr1 + t * NB * MLPH;
        f16x2 hv2[8];
        #pragma unroll
        for (int mp = 0; mp < 8; mp++) {
            float a0 = 0.0f, a1 = 0.0f;
            #pragma unroll
            for (int b = 0; b < NB; b++) {
                float efb = ef[b];
                a0 += efb * W[b * MLPH + 2 * mp + 0];
                a1 += efb * W[b * MLPH + 2 * mp + 1];
            }
            f16x2 v; v.x = (_Float16)silu_f(a0); v.y = (_Float16)silu_f(a1);
            hv2[mp] = v;
        }
        *(float4*)&dst[p * 8 + 0] = *(float4*)&hv2[0];
        *(float4*)&dst[p * 8 + 4] = *(float4*)&hv2[4];
    }
}

// ---------------------------------------------------------------------------
// K3 (fused msg+mix, 16-node tiles, 625 blocks) with SOFTWARE-PIPELINED
// streaming: group g+1's dependent-load chain (crcv/csnd -> hup row) is
// issued before group g's tw compute, hiding ~600cy of latency under
// ~576cy of VALU work. All math identical to the R13/R19-verified body.
// RMODE 0: rep1 + hh=f16(hnew) + hup_out = hnew @ Wup[1].
// RMODE 1: rep2 = silu(hnew @ Wm1).wm2.
// ---------------------------------------------------------------------------
template <int RMODE>
__global__ __launch_bounds__(256) void k_fuse(
    const int* __restrict__ rowptr, const int* __restrict__ csnd,
    const int* __restrict__ crcv, const float* __restrict__ csh,
    const f16x2* __restrict__ chh, const f16x2* __restrict__ wlth,
    const float* __restrict__ hup_in, const f16x8* __restrict__ wf,
    const f16x8* __restrict__ wupf1, half_t* __restrict__ hh,
    const float* __restrict__ wread, const float* __restrict__ Wm1,
    const float* __restrict__ wm2,
    float* __restrict__ hup_out, float* __restrict__ rep)
{
    __shared__ half_t Hs[16 * ROWP];   // 18688 B: f16 agg tile
    __shared__ half_t Hs2[16 * 72];    // 2304 B: f16 hnew tile (RMODE0)

    int lane = threadIdx.x & 63;
    int w = threadIdx.x >> 6;
    int bbase = blockIdx.x * 16;
    int n0 = bbase + w * 4;
    int beg = rowptr[n0], end = rowptr[n0 + 4];

    // per-lane W working set: 72 f16x2 in registers
    f16x2 wreg[8][9];
    #pragma unroll
    for (int mq = 0; mq < 8; mq++)
        #pragma unroll
        for (int jj = 0; jj < 9; jj++)
            wreg[mq][jj] = wlth[mq * CSH + (jj << 6) + lane];

    float acc[9];
    int curRcv = -1;

#define FLUSH() { half_t* ag = &Hs[(curRcv - bbase) * ROWP + lane]; \
    _Pragma("unroll") for (int jj = 0; jj < 9; jj++) ag[jj << 6] = (half_t)acc[jj]; }
#define ZFILL(FROM, TO) for (int zn = (FROM); zn < (TO); zn++) { \
    half_t* ag = &Hs[(zn - bbase) * ROWP + lane]; \
    _Pragma("unroll") for (int jj = 0; jj < 9; jj++) ag[jj << 6] = (half_t)0.0f; }

    // ---- software-pipelined group metadata (next-group prefetch regs) ----
    int nk0, nk1, nk2, nk3, nr0, nr1, nr2, nr3;
    float nh0, nh1, nh2, nh3;
#define LOADG(K0) { \
        nk0 = (K0 + 0 < end) ? K0 + 0 : end - 1; \
        nk1 = (K0 + 1 < end) ? K0 + 1 : end - 1; \
        nk2 = (K0 + 2 < end) ? K0 + 2 : end - 1; \
        nk3 = (K0 + 3 < end) ? K0 + 3 : end - 1; \
        nr0 = crcv[nk0]; nr1 = crcv[nk1]; nr2 = crcv[nk2]; nr3 = crcv[nk3]; \
        nh0 = hup_in[csnd[nk0] * C + lane]; \
        nh1 = hup_in[csnd[nk1] * C + lane]; \
        nh2 = hup_in[csnd[nk2] * C + lane]; \
        nh3 = hup_in[csnd[nk3] * C + lane]; }

    if (beg < end) LOADG(beg)

    for (int k0 = beg; k0 < end; k0 += 4) {
        int nv = end - k0; if (nv > 4) nv = 4;

        // rotate prefetched metadata into current-group regs
        int kc0 = nk0, kc1 = nk1, kc2 = nk2, kc3 = nk3;
        int rcvq0 = nr0, rcvq1 = nr1, rcvq2 = nr2, rcvq3 = nr3;
        float hupq0 = nh0, hupq1 = nh1, hupq2 = nh2, hupq3 = nh3;

        // issue next group's dependent-load chain NOW (hides under tw compute)
        if (k0 + 4 < end) LOADG(k0 + 4)

        float tw0[9], tw1[9], tw2[9], tw3[9];
        #pragma unroll
        for (int jj = 0; jj < 9; jj++) {
            tw0[jj] = 0.f; tw1[jj] = 0.f; tw2[jj] = 0.f; tw3[jj] = 0.f;
        }

        #pragma unroll
        for (int mq = 0; mq < 8; mq++) {
            f16x2 h0 = chh[kc0 * 8 + mq], h1 = chh[kc1 * 8 + mq];
            f16x2 h2 = chh[kc2 * 8 + mq], h3 = chh[kc3 * 8 + mq];
            #pragma unroll
            for (int jj = 0; jj < 9; jj++) {
                f16x2 wv = wreg[mq][jj];
                tw0[jj] = dot2f(h0, wv, tw0[jj]);
                tw1[jj] = dot2f(h1, wv, tw1[jj]);
                tw2[jj] = dot2f(h2, wv, tw2[jj]);
                tw3[jj] = dot2f(h3, wv, tw3[jj]);
            }
        }

#define SCAT(Q) if (Q < nv) { \
        int rcv = rcvq##Q; \
        float hupS = hupq##Q; \
        float4 sA = *(const float4*)&csh[kc##Q * 16]; \
        float4 sB = *(const float4*)&csh[kc##Q * 16 + 4]; \
        float s8v = csh[kc##Q * 16 + 8]; \
        float sh9[9] = {sA.x, sA.y, sA.z, sA.w, sB.x, sB.y, sB.z, sB.w, s8v}; \
        if (rcv != curRcv) { \
            if (curRcv >= 0) { FLUSH(); ZFILL(curRcv + 1, rcv) } else { ZFILL(n0, rcv) } \
            curRcv = rcv; \
            _Pragma("unroll") for (int jj = 0; jj < 9; jj++) acc[jj] = tw##Q[jj] * (hupS * sh9[jj]); \
        } else { \
            _Pragma("unroll") for (int jj = 0; jj < 9; jj++) acc[jj] += tw##Q[jj] * (hupS * sh9[jj]); \
        } }
        SCAT(0) SCAT(1) SCAT(2) SCAT(3)
#undef SCAT
    }
#undef LOADG

    int zfrom = n0;
    if (curRcv >= 0) { FLUSH(); zfrom = curRcv + 1; }
    ZFILL(zfrom, n0 + 4)
#undef FLUSH
#undef ZFILL

    __syncthreads();

    // ---- mix MFMA: wave w -> column tile nt = w ----
    int rowL = lane & 15;
    int kg = (lane >> 4) << 3;
    f32x4 acc4 = {0.f, 0.f, 0.f, 0.f};
    const half_t* hrow = hh + (size_t)(bbase + rowL) * C + kg;
    #pragma unroll
    for (int ks = 0; ks < 20; ks++) {
        f16x8 a = (ks < 18) ? *(const f16x8*)&Hs[rowL * ROWP + ks * 32 + kg]
                            : *(const f16x8*)(hrow + (ks - 18) * 32);
        f16x8 b = wf[(size_t)(ks * 4 + w) * 64 + lane];
        acc4 = __builtin_amdgcn_mfma_f32_16x16x32_f16(a, b, acc4, 0, 0, 0);
    }

    int colb = lane & 15;
    int rq = (lane >> 4) << 2;   // local C/D row base

    __syncthreads();   // all Hs/hh A-reads done before epilogue writes

    if (RMODE == 0) {
        // stage f16 hnew col-slice
        #pragma unroll
        for (int r = 0; r < 4; r++)
            Hs2[(rq + r) * 72 + w * 16 + colb] = (half_t)acc4[r];
        __syncthreads();

        // rep1 by wave 0: lane = seg*16 + row
        if (w == 0) {
            int row = lane & 15, seg = lane >> 4;
            float v = 0.0f;
            #pragma unroll
            for (int j = 0; j < 16; j++)
                v += (float)Hs2[row * 72 + seg * 16 + j] * wread[seg * 16 + j];
            v += __shfl_xor(v, 16);
            v += __shfl_xor(v, 32);
            if (seg == 0) rep[bbase + row] = v;
        }

        // hh (next layer) coalesced copy out
        {
            int idx = threadIdx.x;
            if (idx < 128) {
                int row = idx >> 3, cq = idx & 7;
                *(float4*)&hh[(size_t)(bbase + row) * C + cq * 8] =
                    *(const float4*)&Hs2[row * 72 + cq * 8];
            }
        }

        // hup_out = hnew @ Wup[1]; wave w -> col tile w
        f32x4 u = {0.f, 0.f, 0.f, 0.f};
        #pragma unroll
        for (int ks = 0; ks < 2; ks++) {
            f16x8 a = *(const f16x8*)&Hs2[rowL * 72 + ks * 32 + kg];
            f16x8 b = wupf1[(size_t)(ks * 4 + w) * 64 + lane];
            u = __builtin_amdgcn_mfma_f32_16x16x32_f16(a, b, u, 0, 0, 0);
        }
        #pragma unroll
        for (int r = 0; r < 4; r++)
            hup_out[(size_t)(bbase + rq + r) * C + w * 16 + colb] = u[r];
    } else {
        // reuse Hs space: Hn f32 [16][68] + W1l [64][16]
        float* Hn = (float*)Hs;
        float* W1l = (float*)Hs + 16 * 68;
        for (int t = threadIdx.x; t < C * MLPH; t += 256) W1l[t] = Wm1[t];
        #pragma unroll
        for (int r = 0; r < 4; r++)
            Hn[(rq + r) * 68 + w * 16 + colb] = acc4[r];
        __syncthreads();

        int n = threadIdx.x >> 4, m = threadIdx.x & 15;
        float a2 = 0.0f;
        #pragma unroll 8
        for (int c = 0; c < C; c++) a2 += Hn[n * 68 + c] * W1l[c * MLPH + m];
        float rv = silu_f(a2) * wm2[m];
        rv += __shfl_xor(rv, 1); rv += __shfl_xor(rv, 2);
        rv += __shfl_xor(rv, 4); rv += __shfl_xor(rv, 8);
        if (m == 0) rep[bbase + n] = rv;
    }
}

// ---------------------------------------------------------------------------
extern "C" void kernel_launch(void* const* d_in, const int* in_sizes, int n_in,
                              void* d_out, int out_size, void* d_ws, size_t ws_size,
                              hipStream_t stream) {
    const float* pos    = (const float*)d_in[0];
    const float* na     = (const float*)d_in[1];
    const float* shifts = (const float*)d_in[2];
    const int*   ei     = (const int*)d_in[3];
    const float* ae     = (const float*)d_in[4];
    const float* We     = (const float*)d_in[5];
    const float* Wup    = (const float*)d_in[6];
    const float* Wr1    = (const float*)d_in[7];
    const float* Wr2    = (const float*)d_in[8];
    const float* Wmix   = (const float*)d_in[9];
    const float* Wself  = (const float*)d_in[10];
    const float* wread  = (const float*)d_in[11];
    const float* Wm1    = (const float*)d_in[12];
    const float* wm2    = (const float*)d_in[13];
    float* out = (float*)d_out;

    char* ws = (char*)d_ws;
    size_t off = 0;
    auto alloc = [&](size_t bytes) {
        off = (off + 255) & ~(size_t)255;
        void* p = ws + off;
        off += bytes;
        return p;
    };
    int*   cnt     = (int*)alloc(4);
    int*   deg     = (int*)alloc((size_t)N_NODES * 4);
    int*   rowptr  = (int*)alloc((size_t)(N_NODES + 1) * 4);
    int*   cursor  = (int*)alloc((size_t)N_NODES * 4);
    f16x2* wlth    = (f16x2*)alloc((size_t)2 * 8 * CSH * 4);
    f16x8* wmixf   = (f16x8*)alloc((size_t)2 * 5120 * 16);
    f16x8* wupf    = (f16x8*)alloc((size_t)1024 * 16);
    int*   act_snd = (int*)alloc((size_t)N_EDGES * 4);
    int*   act_rcv = (int*)alloc((size_t)N_EDGES * 4);
    float* act_u   = (float*)alloc((size_t)N_EDGES * 4 * 4);
    float* act_ef  = (float*)alloc((size_t)N_EDGES * 8 * 4);
    int*   csnd    = (int*)alloc((size_t)N_EDGES * 4);
    int*   crcv    = (int*)alloc((size_t)N_EDGES * 4);
    float* csh     = (float*)alloc((size_t)N_EDGES * 16 * 4);
    f16x2* chidh0  = (f16x2*)alloc((size_t)N_EDGES * 8 * 4);
    f16x2* chidh1  = (f16x2*)alloc((size_t)N_EDGES * 8 * 4);
    float* hup     = (float*)alloc((size_t)N_NODES * C * 4);
    float* hup2    = (float*)alloc((size_t)N_NODES * C * 4);
    half_t* hh     = (half_t*)alloc((size_t)N_NODES * C * 2);

    k_zero<<<(N_NODES + 255) / 256, 256, 0, stream>>>(cnt, deg);

    k_edge<<<(N_NODES * C) / 256, 256, 0, stream>>>(pos, shifts, ei, na, We, ae,
                                                    Wr2, Wmix, Wself, Wup,
                                                    cnt, deg, act_snd, act_rcv,
                                                    act_u, act_ef,
                                                    wlth, wmixf, wupf, hh, out);
    k_scan_up<<<1 + (N_NODES / 16 + 15) / 16, 1024, 0, stream>>>(deg, rowptr, cursor,
                                                                 hh, wupf, hup);
    k_scatter<<<N_EDGES / 256, 256, 0, stream>>>(cnt, act_snd, act_rcv,
                                                 act_u, act_ef, Wr1, cursor,
                                                 csnd, crcv, csh, chidh0, chidh1);

    // ---- layer t = 0 (fused msg+mix; epilogue: rep1, hh, hup2) ----
    k_fuse<0><<<N_NODES / 16, 256, 0, stream>>>(rowptr, csnd, crcv, csh,
                                                chidh0, wlth, hup,
                                                wmixf, wupf + 512, hh,
                                                wread, Wm1, wm2,
                                                hup2, out + N_NODES);

    // ---- layer t = 1 (fused msg+mix; epilogue: rep2) ----
    k_fuse<1><<<N_NODES / 16, 256, 0, stream>>>(rowptr, csnd, crcv, csh,
                                                chidh1, wlth + 8 * CSH, hup2,
                                                wmixf + 5120, wupf + 512, hh,
                                                wread, Wm1, wm2,
                                                hup, out + 2 * N_NODES);
}

// Round 22
// 111.773 us; speedup vs baseline: 1.2203x; 1.2203x over previous
//
#include <hip/hip_runtime.h>
#include <math.h>

#define N_NODES 10000
#define N_EDGES 160000
#define NEL 10
#define C 64
#define NB 8
#define SHD 9
#define MLPH 16
#define CSH 576
#define R_MAX 5.0f
#define INV_AVG 0.03125f
#define SCAN_CH2 10    // 1024*10 = 10240 >= N_NODES
#define ROWP  584      // f16 row pitch of LDS agg tile (bank-safe)

typedef _Float16 f16x2 __attribute__((ext_vector_type(2)));
typedef _Float16 f16x8 __attribute__((ext_vector_type(8)));
typedef float    f32x4 __attribute__((ext_vector_type(4)));
typedef _Float16 half_t;

__device__ __forceinline__ float silu_f(float v) {
    return v / (1.0f + __expf(-v));
}

__device__ __forceinline__ float dot2f(f16x2 a, f16x2 b, float c) {
#if __has_builtin(__builtin_amdgcn_fdot2)
    return __builtin_amdgcn_fdot2(a, b, c, false);
#else
    return c + (float)a.x * (float)b.x + (float)a.y * (float)b.y;
#endif
}

// ---------------------------------------------------------------------------
// K0: zero cnt + deg
// ---------------------------------------------------------------------------
__global__ __launch_bounds__(256) void k_zero(
    int* __restrict__ cnt, int* __restrict__ deg)
{
    int i = blockIdx.x * 256 + threadIdx.x;
    if (i == 0) *cnt = 0;
    if (i < N_NODES) deg[i] = 0;
}

// ---------------------------------------------------------------------------
// K1: per-edge geometry + radial basis + compaction + degree histogram +
// fused embed (hh = f16 h) + ALL weight packing on idle blocks (>= 625).
// ---------------------------------------------------------------------------
__global__ __launch_bounds__(256) void k_edge(
    const float* __restrict__ pos, const float* __restrict__ shifts,
    const int* __restrict__ ei,
    const float* __restrict__ na, const float* __restrict__ We,
    const float* __restrict__ ae,
    const float* __restrict__ Wr2, const float* __restrict__ Wmix,
    const float* __restrict__ Wself, const float* __restrict__ Wup,
    int* __restrict__ cnt, int* __restrict__ deg,
    int* __restrict__ act_snd, int* __restrict__ act_rcv,
    float* __restrict__ act_u, float* __restrict__ act_ef,
    f16x2* __restrict__ wlth, f16x8* __restrict__ wmixf, f16x8* __restrict__ wupf,
    half_t* __restrict__ hh, float* __restrict__ out)
{
    int i = blockIdx.x * 256 + threadIdx.x;
    int lane = threadIdx.x & 63;

    // ---- embed: h = na @ We ; out = na @ ae ----
    {
        int n = i >> 6;
        float acc = 0.0f, e0 = 0.0f;
        #pragma unroll
        for (int k = 0; k < NEL; k++) {
            float a = na[n * NEL + k];
            acc += a * We[k * C + lane];
            e0 += a * ae[k];
        }
        hh[i] = (half_t)acc;
        if (lane == 0) out[n] = e0;
    }

    if (blockIdx.x >= N_EDGES / 256) {
        // ---- weight packing on idle blocks ----
        int idx = i - N_EDGES;
        if (idx < 2 * 8 * CSH) {               // wlth: 9216
            int t = idx / (8 * CSH);
            int r = idx - t * (8 * CSH);
            int mq = r / CSH, j = r - mq * CSH;
            int c = j & 63, s = j >> 6;
            float lo = Wr2[t * MLPH * CSH + (2 * mq + 0) * CSH + c * SHD + s];
            float hi = Wr2[t * MLPH * CSH + (2 * mq + 1) * CSH + c * SHD + s];
            f16x2 v; v.x = (_Float16)lo; v.y = (_Float16)hi;
            wlth[idx] = v;
        } else if (idx < 2 * 8 * CSH + 10240) { // wmixf
            int k2 = idx - 2 * 8 * CSH;
            int t = k2 / 5120;
            int r = k2 - t * 5120;
            int ks = r >> 8;
            int rr = r & 255;
            int nt = rr >> 6;
            int ln = rr & 63;
            f16x8 v;
            #pragma unroll
            for (int e = 0; e < 8; e++) {
                int k = ks * 32 + ((ln >> 4) << 3) + e;
                int col = nt * 16 + (ln & 15);
                float x;
                if (k < CSH)
                    x = Wmix[(size_t)t * CSH * C + ((k & 63) * SHD + (k >> 6)) * C + col] * INV_AVG;
                else
                    x = Wself[(size_t)t * C * C + (k - CSH) * C + col];
                v[e] = (_Float16)x;
            }
            wmixf[(size_t)((t * 20 + ks) * 4 + nt) * 64 + ln] = v;
        } else if (idx < 2 * 8 * CSH + 10240 + 1024) {  // wupf
            int k2 = idx - (2 * 8 * CSH + 10240);
            int t = k2 >> 9;
            int r = k2 & 511;
            int ks = r >> 8;
            int rr = r & 255;
            int nt = rr >> 6;
            int ln = rr & 63;
            f16x8 v;
            #pragma unroll
            for (int e = 0; e < 8; e++) {
                int k = ks * 32 + ((ln >> 4) << 3) + e;
                int col = nt * 16 + (ln & 15);
                v[e] = (_Float16)Wup[(size_t)t * C * C + k * C + col];
            }
            wupf[(size_t)((t * 2 + ks) * 4 + nt) * 64 + ln] = v;
        }
        return;
    }

    int e = i;
    int snd = ei[e];
    int rcv = ei[N_EDGES + e];
    float vx = pos[rcv * 3 + 0] - pos[snd * 3 + 0] + shifts[e * 3 + 0];
    float vy = pos[rcv * 3 + 1] - pos[snd * 3 + 1] + shifts[e * 3 + 1];
    float vz = pos[rcv * 3 + 2] - pos[snd * 3 + 2] + shifts[e * 3 + 2];
    float r = sqrtf(vx * vx + vy * vy + vz * vz) + 1e-9f;
    float x = r / R_MAX;
    bool active = x < 1.0f;

    unsigned long long m = __ballot(active);
    int base = 0;
    if (m) {
        int leader = __ffsll((unsigned long long)m) - 1;
        if (lane == leader) base = atomicAdd(cnt, __popcll(m));
        base = __shfl(base, leader);
    }
    if (!active) return;

    int p = base + __popcll(m & ((1ull << lane) - 1ull));
    act_snd[p] = snd;
    act_rcv[p] = rcv;
    atomicAdd(&deg[rcv], 1);

    float inv_r = 1.0f / r;
    *(float4*)&act_u[p * 4] = make_float4(vx * inv_r, vy * inv_r, vz * inv_r, r);

    float x6 = x * x * x; x6 = x6 * x6;
    float x7 = x6 * x;
    float x8 = x7 * x;
    float fc = 1.0f - 28.0f * x6 + 48.0f * x7 - 21.0f * x8;
    float theta = 3.14159265358979323846f * r / R_MAX;
    float s1 = sinf(theta), c1 = cosf(theta);
    float sn = s1, cn = c1;
    float scale = 0.6324555320336759f * inv_r * fc;   // sqrt(2/R_MAX)/r*fc
    float ef[NB];
    ef[0] = scale * sn;
    #pragma unroll
    for (int n = 1; n < NB; n++) {
        float sn1 = sn * c1 + cn * s1;
        float cn1 = cn * c1 - sn * s1;
        sn = sn1; cn = cn1;
        ef[n] = scale * sn;
    }
    *(float4*)&act_ef[p * 8 + 0] = make_float4(ef[0], ef[1], ef[2], ef[3]);
    *(float4*)&act_ef[p * 8 + 4] = make_float4(ef[4], ef[5], ef[6], ef[7]);
}

// ---------------------------------------------------------------------------
// K1b (merged scan + upm): block 0 = exclusive scan of deg -> rowptr+cursor
// (1024 threads). Blocks 1..40: wave W computes hup MFMA tile.
// ---------------------------------------------------------------------------
__global__ __launch_bounds__(1024) void k_scan_up(
    const int* __restrict__ deg, int* __restrict__ rowptr, int* __restrict__ cursor,
    const half_t* __restrict__ hh, const f16x8* __restrict__ wupf,
    float* __restrict__ hup)
{
    int tid = threadIdx.x;

    if (blockIdx.x != 0) {
        int F = (blockIdx.x - 1) * 16 + (tid >> 6);
        if (F >= N_NODES / 16) return;
        int lane = tid & 63;
        int base = F * 16;
        int rowA = base + (lane & 15);
        int kg = (lane >> 4) << 3;

        f32x4 u0 = {0.f,0.f,0.f,0.f}, u1 = {0.f,0.f,0.f,0.f};
        f32x4 u2 = {0.f,0.f,0.f,0.f}, u3 = {0.f,0.f,0.f,0.f};
        const half_t* hrow = hh + (size_t)rowA * C + kg;
        #pragma unroll
        for (int ks = 0; ks < 2; ks++) {
            f16x8 a = *(const f16x8*)(hrow + ks * 32);
            const f16x8* bp = wupf + (size_t)(ks * 4) * 64 + lane;
            u0 = __builtin_amdgcn_mfma_f32_16x16x32_f16(a, bp[0],   u0, 0, 0, 0);
            u1 = __builtin_amdgcn_mfma_f32_16x16x32_f16(a, bp[64],  u1, 0, 0, 0);
            u2 = __builtin_amdgcn_mfma_f32_16x16x32_f16(a, bp[128], u2, 0, 0, 0);
            u3 = __builtin_amdgcn_mfma_f32_16x16x32_f16(a, bp[192], u3, 0, 0, 0);
        }
        int colb = lane & 15;
        int rowb = base + ((lane >> 4) << 2);
        #pragma unroll
        for (int r = 0; r < 4; r++) {
            float* hp = hup + (size_t)(rowb + r) * C + colb;
            hp[0]  = u0[r];
            hp[16] = u1[r];
            hp[32] = u2[r];
            hp[48] = u3[r];
        }
        return;
    }

    __shared__ int dl[N_NODES];   // 40000 B
    __shared__ int part[1024];    // 4096 B
    for (int i = tid; i < N_NODES; i += 1024) dl[i] = deg[i];
    __syncthreads();

    int base = tid * SCAN_CH2;
    int s = 0;
    #pragma unroll
    for (int i = 0; i < SCAN_CH2; i++) {
        int idx = base + i;
        if (idx < N_NODES) s += dl[idx];
    }
    part[tid] = s;
    __syncthreads();
    for (int off = 1; off < 1024; off <<= 1) {
        int v = (tid >= off) ? part[tid - off] : 0;
        __syncthreads();
        part[tid] += v;
        __syncthreads();
    }
    int run = part[tid] - s;
    #pragma unroll
    for (int i = 0; i < SCAN_CH2; i++) {
        int idx = base + i;
        if (idx < N_NODES) {
            int v = dl[idx];
            dl[idx] = run;
            run += v;
        }
    }
    __syncthreads();
    for (int i = tid; i < N_NODES; i += 1024) {
        int r = dl[i];
        rowptr[i] = r;
        cursor[i] = r;
    }
    if (tid == 1023) rowptr[N_NODES] = part[1023];
}

// ---------------------------------------------------------------------------
// K1c (merged rank+permute): scatter payloads into CSR order directly.
// ---------------------------------------------------------------------------
__global__ __launch_bounds__(256) void k_scatter(
    const int* __restrict__ cnt, const int* __restrict__ act_snd,
    const int* __restrict__ act_rcv, const float* __restrict__ act_u,
    const float* __restrict__ act_ef, const float* __restrict__ Wr1,
    int* __restrict__ cursor,
    int* __restrict__ csnd, int* __restrict__ crcv, float* __restrict__ csh,
    f16x2* __restrict__ chidh0, f16x2* __restrict__ chidh1)
{
    int i = blockIdx.x * 256 + threadIdx.x;
    if (i >= *cnt) return;
    int rcv = act_rcv[i];
    int p = atomicAdd(&cursor[rcv], 1);

    csnd[p] = act_snd[i];
    crcv[p] = rcv;

    float4 u4 = *(const float4*)&act_u[i * 4];
    float ux = u4.x, uy = u4.y, uz = u4.z;
    const float s3 = 1.7320508075688772f;
    const float s5 = 2.23606797749979f;
    const float s15 = 3.872983346207417f;
    *(float4*)&csh[p * 16 + 0] = make_float4(1.0f, s3 * ux, s3 * uy, s3 * uz);
    *(float4*)&csh[p * 16 + 4] = make_float4(s15 * ux * uy, s15 * uy * uz,
                                             0.5f * s5 * (3.0f * uz * uz - 1.0f),
                                             s15 * ux * uz);
    csh[p * 16 + 8] = 0.5f * s15 * (ux * ux - uy * uy);

    float4 e0 = *(const float4*)&act_ef[i * 8 + 0];
    float4 e1 = *(const float4*)&act_ef[i * 8 + 4];
    float ef[NB] = {e0.x, e0.y, e0.z, e0.w, e1.x, e1.y, e1.z, e1.w};

    #pragma unroll
    for (int t = 0; t < 2; t++) {
        f16x2* dst = (t == 0) ? chidh0 : chidh1;
        const float* W = Wr1 + t * NB * MLPH;
        f16x2 hv2[8];
        #pragma unroll
        for (int mp = 0; mp < 8; mp++) {
            float a0 = 0.0f, a1 = 0.0f;
            #pragma unroll
            for (int b = 0; b < NB; b++) {
                float efb = ef[b];
                a0 += efb * W[b * MLPH + 2 * mp + 0];
                a1 += efb * W[b * MLPH + 2 * mp + 1];
            }
            f16x2 v; v.x = (_Float16)silu_f(a0); v.y = (_Float16)silu_f(a1);
            hv2[mp] = v;
        }
        *(float4*)&dst[p * 8 + 0] = *(float4*)&hv2[0];
        *(float4*)&dst[p * 8 + 4] = *(float4*)&hv2[4];
    }
}

// ---------------------------------------------------------------------------
// K3 (fused msg+mix, 16-node tiles, 625 blocks — R13/R19-verified shape):
// wave w owns 4 nodes, streams CSR edges with register-W into LDS f16 agg
// tile; then 4 waves each take one 16-col MFMA tile of
// hnew = [agg|hh] @ [Wmix/32;Wself].
// RMODE 0: rep1 + hh=f16(hnew) + hup_out = hnew @ Wup[1].
// RMODE 1: rep2 = silu(hnew @ Wm1).wm2.
// ---------------------------------------------------------------------------
template <int RMODE>
__global__ __launch_bounds__(256) void k_fuse(
    const int* __restrict__ rowptr, const int* __restrict__ csnd,
    const int* __restrict__ crcv, const float* __restrict__ csh,
    const f16x2* __restrict__ chh, const f16x2* __restrict__ wlth,
    const float* __restrict__ hup_in, const f16x8* __restrict__ wf,
    const f16x8* __restrict__ wupf1, half_t* __restrict__ hh,
    const float* __restrict__ wread, const float* __restrict__ Wm1,
    const float* __restrict__ wm2,
    float* __restrict__ hup_out, float* __restrict__ rep)
{
    __shared__ half_t Hs[16 * ROWP];   // 18688 B: f16 agg tile
    __shared__ half_t Hs2[16 * 72];    // 2304 B: f16 hnew tile (RMODE0)

    int lane = threadIdx.x & 63;
    int w = threadIdx.x >> 6;
    int bbase = blockIdx.x * 16;
    int n0 = bbase + w * 4;
    int beg = rowptr[n0], end = rowptr[n0 + 4];

    // per-lane W working set: 72 f16x2 in registers
    f16x2 wreg[8][9];
    #pragma unroll
    for (int mq = 0; mq < 8; mq++)
        #pragma unroll
        for (int jj = 0; jj < 9; jj++)
            wreg[mq][jj] = wlth[mq * CSH + (jj << 6) + lane];

    float acc[9];
    int curRcv = -1;

#define FLUSH() { half_t* ag = &Hs[(curRcv - bbase) * ROWP + lane]; \
    _Pragma("unroll") for (int jj = 0; jj < 9; jj++) ag[jj << 6] = (half_t)acc[jj]; }
#define ZFILL(FROM, TO) for (int zn = (FROM); zn < (TO); zn++) { \
    half_t* ag = &Hs[(zn - bbase) * ROWP + lane]; \
    _Pragma("unroll") for (int jj = 0; jj < 9; jj++) ag[jj << 6] = (half_t)0.0f; }

    for (int k0 = beg; k0 < end; k0 += 4) {
        int nv = end - k0; if (nv > 4) nv = 4;

#define PRE(Q) int kc##Q = (k0 + Q < end) ? k0 + Q : end - 1; \
        int rcvq##Q = crcv[kc##Q]; \
        float hupq##Q = hup_in[csnd[kc##Q] * C + lane];
        PRE(0) PRE(1) PRE(2) PRE(3)
#undef PRE

        float tw0[9], tw1[9], tw2[9], tw3[9];
        #pragma unroll
        for (int jj = 0; jj < 9; jj++) {
            tw0[jj] = 0.f; tw1[jj] = 0.f; tw2[jj] = 0.f; tw3[jj] = 0.f;
        }

        #pragma unroll
        for (int mq = 0; mq < 8; mq++) {
            f16x2 h0 = chh[kc0 * 8 + mq], h1 = chh[kc1 * 8 + mq];
            f16x2 h2 = chh[kc2 * 8 + mq], h3 = chh[kc3 * 8 + mq];
            #pragma unroll
            for (int jj = 0; jj < 9; jj++) {
                f16x2 wv = wreg[mq][jj];
                tw0[jj] = dot2f(h0, wv, tw0[jj]);
                tw1[jj] = dot2f(h1, wv, tw1[jj]);
                tw2[jj] = dot2f(h2, wv, tw2[jj]);
                tw3[jj] = dot2f(h3, wv, tw3[jj]);
            }
        }

#define SCAT(Q) if (Q < nv) { \
        int rcv = rcvq##Q; \
        float hupS = hupq##Q; \
        float4 sA = *(const float4*)&csh[kc##Q * 16]; \
        float4 sB = *(const float4*)&csh[kc##Q * 16 + 4]; \
        float s8v = csh[kc##Q * 16 + 8]; \
        float sh9[9] = {sA.x, sA.y, sA.z, sA.w, sB.x, sB.y, sB.z, sB.w, s8v}; \
        if (rcv != curRcv) { \
            if (curRcv >= 0) { FLUSH(); ZFILL(curRcv + 1, rcv) } else { ZFILL(n0, rcv) } \
            curRcv = rcv; \
            _Pragma("unroll") for (int jj = 0; jj < 9; jj++) acc[jj] = tw##Q[jj] * (hupS * sh9[jj]); \
        } else { \
            _Pragma("unroll") for (int jj = 0; jj < 9; jj++) acc[jj] += tw##Q[jj] * (hupS * sh9[jj]); \
        } }
        SCAT(0) SCAT(1) SCAT(2) SCAT(3)
#undef SCAT
    }

    int zfrom = n0;
    if (curRcv >= 0) { FLUSH(); zfrom = curRcv + 1; }
    ZFILL(zfrom, n0 + 4)
#undef FLUSH
#undef ZFILL

    __syncthreads();

    // ---- mix MFMA: wave w -> column tile nt = w ----
    int rowL = lane & 15;
    int kg = (lane >> 4) << 3;
    f32x4 acc4 = {0.f, 0.f, 0.f, 0.f};
    const half_t* hrow = hh + (size_t)(bbase + rowL) * C + kg;
    #pragma unroll
    for (int ks = 0; ks < 20; ks++) {
        f16x8 a = (ks < 18) ? *(const f16x8*)&Hs[rowL * ROWP + ks * 32 + kg]
                            : *(const f16x8*)(hrow + (ks - 18) * 32);
        f16x8 b = wf[(size_t)(ks * 4 + w) * 64 + lane];
        acc4 = __builtin_amdgcn_mfma_f32_16x16x32_f16(a, b, acc4, 0, 0, 0);
    }

    int colb = lane & 15;
    int rq = (lane >> 4) << 2;   // local C/D row base

    __syncthreads();   // all Hs/hh A-reads done before epilogue writes

    if (RMODE == 0) {
        // stage f16 hnew col-slice
        #pragma unroll
        for (int r = 0; r < 4; r++)
            Hs2[(rq + r) * 72 + w * 16 + colb] = (half_t)acc4[r];
        __syncthreads();

        // rep1 by wave 0: lane = seg*16 + row
        if (w == 0) {
            int row = lane & 15, seg = lane >> 4;
            float v = 0.0f;
            #pragma unroll
            for (int j = 0; j < 16; j++)
                v += (float)Hs2[row * 72 + seg * 16 + j] * wread[seg * 16 + j];
            v += __shfl_xor(v, 16);
            v += __shfl_xor(v, 32);
            if (seg == 0) rep[bbase + row] = v;
        }

        // hh (next layer) coalesced copy out
        {
            int idx = threadIdx.x;
            if (idx < 128) {
                int row = idx >> 3, cq = idx & 7;
                *(float4*)&hh[(size_t)(bbase + row) * C + cq * 8] =
                    *(const float4*)&Hs2[row * 72 + cq * 8];
            }
        }

        // hup_out = hnew @ Wup[1]; wave w -> col tile w
        f32x4 u = {0.f, 0.f, 0.f, 0.f};
        #pragma unroll
        for (int ks = 0; ks < 2; ks++) {
            f16x8 a = *(const f16x8*)&Hs2[rowL * 72 + ks * 32 + kg];
            f16x8 b = wupf1[(size_t)(ks * 4 + w) * 64 + lane];
            u = __builtin_amdgcn_mfma_f32_16x16x32_f16(a, b, u, 0, 0, 0);
        }
        #pragma unroll
        for (int r = 0; r < 4; r++)
            hup_out[(size_t)(bbase + rq + r) * C + w * 16 + colb] = u[r];
    } else {
        // reuse Hs space: Hn f32 [16][68] + W1l [64][16]
        float* Hn = (float*)Hs;
        float* W1l = (float*)Hs + 16 * 68;
        for (int t = threadIdx.x; t < C * MLPH; t += 256) W1l[t] = Wm1[t];
        #pragma unroll
        for (int r = 0; r < 4; r++)
            Hn[(rq + r) * 68 + w * 16 + colb] = acc4[r];
        __syncthreads();

        int n = threadIdx.x >> 4, m = threadIdx.x & 15;
        float a2 = 0.0f;
        #pragma unroll 8
        for (int c = 0; c < C; c++) a2 += Hn[n * 68 + c] * W1l[c * MLPH + m];
        float rv = silu_f(a2) * wm2[m];
        rv += __shfl_xor(rv, 1); rv += __shfl_xor(rv, 2);
        rv += __shfl_xor(rv, 4); rv += __shfl_xor(rv, 8);
        if (m == 0) rep[bbase + n] = rv;
    }
}

// ---------------------------------------------------------------------------
extern "C" void kernel_launch(void* const* d_in, const int* in_sizes, int n_in,
                              void* d_out, int out_size, void* d_ws, size_t ws_size,
                              hipStream_t stream) {
    const float* pos    = (const float*)d_in[0];
    const float* na     = (const float*)d_in[1];
    const float* shifts = (const float*)d_in[2];
    const int*   ei     = (const int*)d_in[3];
    const float* ae     = (const float*)d_in[4];
    const float* We     = (const float*)d_in[5];
    const float* Wup    = (const float*)d_in[6];
    const float* Wr1    = (const float*)d_in[7];
    const float* Wr2    = (const float*)d_in[8];
    const float* Wmix   = (const float*)d_in[9];
    const float* Wself  = (const float*)d_in[10];
    const float* wread  = (const float*)d_in[11];
    const float* Wm1    = (const float*)d_in[12];
    const float* wm2    = (const float*)d_in[13];
    float* out = (float*)d_out;

    char* ws = (char*)d_ws;
    size_t off = 0;
    auto alloc = [&](size_t bytes) {
        off = (off + 255) & ~(size_t)255;
        void* p = ws + off;
        off += bytes;
        return p;
    };
    int*   cnt     = (int*)alloc(4);
    int*   deg     = (int*)alloc((size_t)N_NODES * 4);
    int*   rowptr  = (int*)alloc((size_t)(N_NODES + 1) * 4);
    int*   cursor  = (int*)alloc((size_t)N_NODES * 4);
    f16x2* wlth    = (f16x2*)alloc((size_t)2 * 8 * CSH * 4);
    f16x8* wmixf   = (f16x8*)alloc((size_t)2 * 5120 * 16);
    f16x8* wupf    = (f16x8*)alloc((size_t)1024 * 16);
    int*   act_snd = (int*)alloc((size_t)N_EDGES * 4);
    int*   act_rcv = (int*)alloc((size_t)N_EDGES * 4);
    float* act_u   = (float*)alloc((size_t)N_EDGES * 4 * 4);
    float* act_ef  = (float*)alloc((size_t)N_EDGES * 8 * 4);
    int*   csnd    = (int*)alloc((size_t)N_EDGES * 4);
    int*   crcv    = (int*)alloc((size_t)N_EDGES * 4);
    float* csh     = (float*)alloc((size_t)N_EDGES * 16 * 4);
    f16x2* chidh0  = (f16x2*)alloc((size_t)N_EDGES * 8 * 4);
    f16x2* chidh1  = (f16x2*)alloc((size_t)N_EDGES * 8 * 4);
    float* hup     = (float*)alloc((size_t)N_NODES * C * 4);
    float* hup2    = (float*)alloc((size_t)N_NODES * C * 4);
    half_t* hh     = (half_t*)alloc((size_t)N_NODES * C * 2);

    k_zero<<<(N_NODES + 255) / 256, 256, 0, stream>>>(cnt, deg);

    k_edge<<<(N_NODES * C) / 256, 256, 0, stream>>>(pos, shifts, ei, na, We, ae,
                                                    Wr2, Wmix, Wself, Wup,
                                                    cnt, deg, act_snd, act_rcv,
                                                    act_u, act_ef,
                                                    wlth, wmixf, wupf, hh, out);
    k_scan_up<<<1 + (N_NODES / 16 + 15) / 16, 1024, 0, stream>>>(deg, rowptr, cursor,
                                                                 hh, wupf, hup);
    k_scatter<<<N_EDGES / 256, 256, 0, stream>>>(cnt, act_snd, act_rcv,
                                                 act_u, act_ef, Wr1, cursor,
                                                 csnd, crcv, csh, chidh0, chidh1);

    // ---- layer t = 0 (fused msg+mix; epilogue: rep1, hh, hup2) ----
    k_fuse<0><<<N_NODES / 16, 256, 0, stream>>>(rowptr, csnd, crcv, csh,
                                                chidh0, wlth, hup,
                                                wmixf, wupf + 512, hh,
                                                wread, Wm1, wm2,
                                                hup2, out + N_NODES);

    // ---- layer t = 1 (fused msg+mix; epilogue: rep2) ----
    k_fuse<1><<<N_NODES / 16, 256, 0, stream>>>(rowptr, csnd, crcv, csh,
                                                chidh1, wlth + 8 * CSH, hup2,
                                                wmixf + 5120, wupf + 512, hh,
                                                wread, Wm1, wm2,
                                                hup, out + 2 * N_NODES);
}